// Round 4
// baseline (679.992 us; speedup 1.0000x reference)
//
#include <hip/hip_runtime.h>
#include <math.h>

constexpr int BATCH = 4096;
constexpr int D_IN  = 784;
constexpr int F     = 512;
constexpr int NEC   = 512;   // codebook entries

// ---------------- zero init (doubles) ----------------
__global__ void k_zero_d(double* p, int n) {
    int i = blockIdx.x * blockDim.x + threadIdx.x;
    if (i < n) p[i] = 0.0;
}

// ---- GEMM (NT) emulating BLAS sgemm: per-output sequential-k fma chain
// ---- within KC-panels (runtime KC), panel partials combined in order with fp32 adds.
// ---- Optional BN transform on A: a' = ((a - mu)*rs)*gamma + beta (np rounding).
template<bool RELU, bool BN>
__global__ __launch_bounds__(256) void k_gemm_np(
    const float* __restrict__ A, const float* __restrict__ Bw, float* __restrict__ C,
    int M, int N, int K, int KC,
    const float* __restrict__ mu, const float* __restrict__ rs,
    const float* __restrict__ gamma, const float* __restrict__ beta)
{
    __shared__ float As[16][68];
    __shared__ float Bs[16][68];
    const int t  = threadIdx.x;
    const int bm = blockIdx.y * 64, bn = blockIdx.x * 64;
    const int tm = (t >> 4) * 4, tn = (t & 15) * 4;
    const int rA = t >> 2;
    const int c4 = (t & 3) * 4;
    const float* Arow = A + (size_t)(bm + rA) * K;
    const float* Brow = Bw + (size_t)(bn + rA) * K;
    float tot[4][4];
    float accp[4][4] = {};
    bool first = true;
    for (int k0 = 0; k0 < K; k0 += 16) {
        float4 af = *reinterpret_cast<const float4*>(Arow + k0 + c4);
        float4 bf = *reinterpret_cast<const float4*>(Brow + k0 + c4);
        float av[4] = {af.x, af.y, af.z, af.w};
        if (BN) {
            #pragma unroll
            for (int u = 0; u < 4; ++u) {
                const int k = k0 + c4 + u;
                float d = __fsub_rn(av[u], mu[k]);
                d = __fmul_rn(d, rs[k]);
                d = __fmul_rn(d, gamma[k]);
                av[u] = __fadd_rn(d, beta[k]);
            }
        }
        As[c4 + 0][rA] = av[0]; As[c4 + 1][rA] = av[1];
        As[c4 + 2][rA] = av[2]; As[c4 + 3][rA] = av[3];
        Bs[c4 + 0][rA] = bf.x;  Bs[c4 + 1][rA] = bf.y;
        Bs[c4 + 2][rA] = bf.z;  Bs[c4 + 3][rA] = bf.w;
        __syncthreads();
        #pragma unroll
        for (int kk = 0; kk < 16; ++kk) {
            float4 a4 = *reinterpret_cast<const float4*>(&As[kk][tm]);
            float4 b4 = *reinterpret_cast<const float4*>(&Bs[kk][tn]);
            float aa[4] = {a4.x, a4.y, a4.z, a4.w};
            float bb[4] = {b4.x, b4.y, b4.z, b4.w};
            #pragma unroll
            for (int i = 0; i < 4; ++i)
                #pragma unroll
                for (int j = 0; j < 4; ++j)
                    accp[i][j] = fmaf(aa[i], bb[j], accp[i][j]);
        }
        __syncthreads();
        const int kend = k0 + 16;
        if ((kend % KC) == 0 || kend == K) {   // panel boundary: fold partial
            #pragma unroll
            for (int i = 0; i < 4; ++i)
                #pragma unroll
                for (int j = 0; j < 4; ++j) {
                    tot[i][j] = first ? accp[i][j] : __fadd_rn(tot[i][j], accp[i][j]);
                    accp[i][j] = 0.f;
                }
            first = false;
        }
    }
    #pragma unroll
    for (int i = 0; i < 4; ++i) {
        float r0 = RELU ? fmaxf(tot[i][0], 0.f) : tot[i][0];
        float r1 = RELU ? fmaxf(tot[i][1], 0.f) : tot[i][1];
        float r2 = RELU ? fmaxf(tot[i][2], 0.f) : tot[i][2];
        float r3 = RELU ? fmaxf(tot[i][3], 0.f) : tot[i][3];
        float4 r = make_float4(r0, r1, r2, r3);
        *reinterpret_cast<float4*>(&C[(size_t)(bm + tm + i) * N + bn + tn]) = r;
    }
}

// ---------------- wave reduce helper (fp64) ----------------
__device__ __forceinline__ double wave_reduce_add(double v) {
    #pragma unroll
    for (int off = 32; off; off >>= 1) v += __shfl_xor(v, off);
    return v;
}

// ---------------- fq21: dim-8 VQ, numpy-fp32-exact dist ----------------
__global__ __launch_bounds__(256) void k_fq21_np(
    const float* __restrict__ h, const float* __restrict__ E,
    float* __restrict__ qx, double* __restrict__ dacc)
{
    __shared__ float Es[NEC][8];
    __shared__ float Cn[NEC];
    const int t = threadIdx.x;
    for (int i = t; i < 8 * NEC; i += 256) Es[i & (NEC - 1)][i >> 9] = E[i];
    __syncthreads();
    for (int n = t; n < NEC; n += 256) {
        float c = __fmul_rn(Es[n][0], Es[n][0]);
        #pragma unroll
        for (int j = 1; j < 8; ++j)
            c = __fadd_rn(c, __fmul_rn(Es[n][j], Es[n][j]));
        Cn[n] = c;
    }
    __syncthreads();
    const int idx = blockIdx.x * 256 + t;
    const int b = idx >> 6, c = idx & 63;
    const float* hb = h + (size_t)b * F + c;
    float v[8];
    #pragma unroll
    for (int j = 0; j < 8; ++j) v[j] = hb[j * 64];
    float s[8];
    #pragma unroll
    for (int j = 0; j < 8; ++j) s[j] = __fmul_rn(v[j], v[j]);
    // numpy pairwise n=8: ((s0+s1)+(s2+s3)) + ((s4+s5)+(s6+s7))
    const float Aterm = __fadd_rn(
        __fadd_rn(__fadd_rn(s[0], s[1]), __fadd_rn(s[2], s[3])),
        __fadd_rn(__fadd_rn(s[4], s[5]), __fadd_rn(s[6], s[7])));
    float best = 3.4e38f; int bi = 0;
    for (int n = 0; n < NEC; ++n) {
        float4 e0 = *reinterpret_cast<const float4*>(&Es[n][0]);
        float4 e1 = *reinterpret_cast<const float4*>(&Es[n][4]);
        float bsum = __fmul_rn(v[0], e0.x);
        bsum = fmaf(v[1], e0.y, bsum);
        bsum = fmaf(v[2], e0.z, bsum);
        bsum = fmaf(v[3], e0.w, bsum);
        bsum = fmaf(v[4], e1.x, bsum);
        bsum = fmaf(v[5], e1.y, bsum);
        bsum = fmaf(v[6], e1.z, bsum);
        bsum = fmaf(v[7], e1.w, bsum);
        float d = __fadd_rn(__fsub_rn(Aterm, __fadd_rn(bsum, bsum)), Cn[n]);
        if (d < best) { best = d; bi = n; }
    }
    double dsum = 0.0;
    float* qb = qx + (size_t)b * F + c;
    #pragma unroll
    for (int j = 0; j < 8; ++j) {
        float df = __fsub_rn(Es[bi][j], v[j]);   // fl(q - x)
        dsum += (double)df * (double)df;
        qb[j * 64] = __fadd_rn(v[j], df);        // fl(x + fl(q - x))
    }
    dsum = wave_reduce_add(dsum);
    if ((t & 63) == 0) atomicAdd(dacc, dsum);
}

// ---------------- weight quantization: dim-16 VQ, numpy-fp32-exact ----------------
__global__ __launch_bounds__(256) void k_wq_np(
    const float* __restrict__ W2, const float* __restrict__ E,
    float* __restrict__ qW2, double* __restrict__ dacc)
{
    __shared__ float Es[NEC][16];
    __shared__ float Cn[NEC];
    const int t = threadIdx.x;
    for (int i = t; i < 16 * NEC; i += 256) Es[i & (NEC - 1)][i >> 9] = E[i];
    __syncthreads();
    for (int n = t; n < NEC; n += 256) {
        float c = __fmul_rn(Es[n][0], Es[n][0]);
        #pragma unroll
        for (int j = 1; j < 16; ++j)
            c = __fadd_rn(c, __fmul_rn(Es[n][j], Es[n][j]));
        Cn[n] = c;
    }
    __syncthreads();
    const int idx = blockIdx.x * 256 + t;   // 16384 vectors
    const int g = idx >> 6, c = idx & 63;
    float v[16];
    #pragma unroll
    for (int k = 0; k < 16; ++k)
        v[k] = W2[(size_t)(2 * g + (k & 1)) * F + 8 * c + (k >> 1)];
    float s[16];
    #pragma unroll
    for (int k = 0; k < 16; ++k) s[k] = __fmul_rn(v[k], v[k]);
    // numpy pairwise n=16: r_j = s_j + s_{j+8}; then 8-tree
    float r[8];
    #pragma unroll
    for (int j = 0; j < 8; ++j) r[j] = __fadd_rn(s[j], s[j + 8]);
    const float Aterm = __fadd_rn(
        __fadd_rn(__fadd_rn(r[0], r[1]), __fadd_rn(r[2], r[3])),
        __fadd_rn(__fadd_rn(r[4], r[5]), __fadd_rn(r[6], r[7])));
    float best = 3.4e38f; int bi = 0;
    for (int n = 0; n < NEC; ++n) {
        float bsum = __fmul_rn(v[0], Es[n][0]);
        #pragma unroll
        for (int k = 1; k < 16; ++k) bsum = fmaf(v[k], Es[n][k], bsum);
        float d = __fadd_rn(__fsub_rn(Aterm, __fadd_rn(bsum, bsum)), Cn[n]);
        if (d < best) { best = d; bi = n; }
    }
    double dsum = 0.0;
    #pragma unroll
    for (int k = 0; k < 16; ++k) {
        float df = __fsub_rn(Es[bi][k], v[k]);
        dsum += (double)df * (double)df;
        qW2[(size_t)(2 * g + (k & 1)) * F + 8 * c + (k >> 1)] = __fadd_rn(v[k], df);
    }
    dsum = wave_reduce_add(dsum);
    if ((t & 63) == 0) atomicAdd(dacc, dsum);
}

// ---------------- BN stats: numpy sequential fp32 over rows ----------------
__global__ void k_bn(const float* __restrict__ qx, float* __restrict__ mu, float* __restrict__ rs)
{
    int f = blockIdx.x * blockDim.x + threadIdx.x;
    if (f >= F) return;
    float acc = 0.f;
    for (int r = 0; r < BATCH; ++r) acc = __fadd_rn(acc, qx[(size_t)r * F + f]);
    float m = __fmul_rn(acc, 1.f / 4096.f);   // exact (/2^12)
    float acc2 = 0.f;
    for (int r = 0; r < BATCH; ++r) {
        float d = __fsub_rn(qx[(size_t)r * F + f], m);
        acc2 = __fadd_rn(acc2, __fmul_rn(d, d));
    }
    float var = __fmul_rn(acc2, 1.f / 4096.f);
    float w = __fadd_rn(var, 1e-5f);
    mu[f] = m;
    rs[f] = __fdiv_rn(1.0f, __fsqrt_rn(w));
}

// ---------------- fq22: dim-2 VQ, numpy-fp32-exact ----------------
__global__ __launch_bounds__(256) void k_fq22_np(
    const float* __restrict__ h2, const float* __restrict__ E,
    float* __restrict__ qx2, double* __restrict__ dacc)
{
    __shared__ float2 Es[NEC];
    __shared__ float Cn[NEC];
    const int t = threadIdx.x;
    for (int n = t; n < NEC; n += 256) {
        float e0 = E[n], e1 = E[NEC + n];
        Es[n] = make_float2(e0, e1);
        Cn[n] = __fadd_rn(__fmul_rn(e0, e0), __fmul_rn(e1, e1));
    }
    __syncthreads();
    const int b = blockIdx.x;
    const float v0 = h2[(size_t)b * F + t];
    const float v1 = h2[(size_t)b * F + 256 + t];
    const float Aterm = __fadd_rn(__fmul_rn(v0, v0), __fmul_rn(v1, v1));
    float best = 3.4e38f; int bi = 0;
    #pragma unroll 4
    for (int n = 0; n < NEC; ++n) {
        float2 e = Es[n];
        float bsum = fmaf(v1, e.y, __fmul_rn(v0, e.x));   // k=2 fma chain
        float d = __fadd_rn(__fsub_rn(Aterm, __fadd_rn(bsum, bsum)), Cn[n]);
        if (d < best) { best = d; bi = n; }
    }
    float2 eb = Es[bi];
    float d0 = __fsub_rn(eb.x, v0), d1 = __fsub_rn(eb.y, v1);
    qx2[(size_t)b * F + t]       = __fadd_rn(v0, d0);
    qx2[(size_t)b * F + 256 + t] = __fadd_rn(v1, d1);
    double dsum = (double)d0 * d0 + (double)d1 * d1;
    dsum = wave_reduce_add(dsum);
    if ((t & 63) == 0) atomicAdd(dacc, dsum);
}

// ---------------- final thin GEMM: out[b,o] = sum_i qx2[b,i] * W3[o,i] ----------------
__global__ __launch_bounds__(256) void k_gemm3(
    const float* __restrict__ qx2, const float* __restrict__ W3, float* __restrict__ out)
{
    __shared__ float Ws[10 * F];
    const int t = threadIdx.x;
    for (int i = t; i < 10 * F; i += 256) Ws[i] = W3[i];
    __syncthreads();
    const int w = t >> 6, l = t & 63;
    const int b = blockIdx.x * 4 + w;
    const float* xb = qx2 + (size_t)b * F;
    double acc[10] = {};
    for (int i = l; i < F; i += 64) {
        double xv = (double)xb[i];
        #pragma unroll
        for (int o = 0; o < 10; ++o) acc[o] = fma(xv, (double)Ws[o * F + i], acc[o]);
    }
    #pragma unroll
    for (int o = 0; o < 10; ++o) {
        double a = wave_reduce_add(acc[o]);
        if (l == 0) out[(size_t)b * 10 + o] = (float)a;
    }
}

// ---------------- diff scalar ----------------
__global__ void k_findiff(const double* __restrict__ dacc, float* __restrict__ out)
{
    if (threadIdx.x == 0) {
        double d21 = dacc[0] * (1.0 / 2097152.0);   // 4096*64*8
        double dq  = dacc[1] * (1.0 / 262144.0);    // 256*64*16
        double d22 = dacc[2] * (1.0 / 2097152.0);   // 4096*256*2
        out[BATCH * 10] = (float)((d21 + d22) + dq);
    }
}

extern "C" void kernel_launch(void* const* d_in, const int* in_sizes, int n_in,
                              void* d_out, int out_size, void* d_ws, size_t ws_size,
                              hipStream_t stream)
{
    const float* x     = (const float*)d_in[0];
    const float* W1    = (const float*)d_in[1];
    const float* W2    = (const float*)d_in[2];
    const float* W3    = (const float*)d_in[3];
    const float* gamma = (const float*)d_in[4];
    const float* beta  = (const float*)d_in[5];
    const float* E1    = (const float*)d_in[6];   // [8,512]
    const float* E2    = (const float*)d_in[7];   // [16,512]
    const float* E3    = (const float*)d_in[8];   // [2,512]
    float* out = (float*)d_out;

    const int KC = 512;   // BLIS/AOCL zen KC (and OpenBLAS-ZEN-if-Q512); r3 tried 384 (failed)

    char* ws = (char*)d_ws;
    float*  hf   = (float*)ws;                                 // 8 MB (h, then h2)
    float*  qxf  = (float*)(ws + (size_t) 8 * 1024 * 1024);    // 8 MB (qx, then qx2)
    float*  qW2f = (float*)(ws + (size_t)16 * 1024 * 1024);    // 1 MB
    float*  muf  = (float*)(ws + (size_t)17 * 1024 * 1024);    // 512 f32
    float*  rsf  = muf + F;                                    // 512 f32
    double* dacc = (double*)(ws + (size_t)17 * 1024 * 1024 + 4096);  // 3 doubles

    k_zero_d<<<1, 64, 0, stream>>>(dacc, 3);
    // h = relu(x @ W1^T)  — sgemm emulation, KC panels (784 = 512 + 272)
    k_gemm_np<true, false><<<dim3(F / 64, BATCH / 64), 256, 0, stream>>>(
        x, W1, hf, BATCH, F, D_IN, KC, nullptr, nullptr, nullptr, nullptr);
    // fq21 -> qx
    k_fq21_np<<<BATCH * 64 / 256, 256, 0, stream>>>(hf, E1, qxf, dacc + 0);
    // weight quantization -> qW2
    k_wq_np<<<64, 256, 0, stream>>>(W2, E2, qW2f, dacc + 1);
    // BN stats (sequential fp32, numpy order)
    k_bn<<<2, 256, 0, stream>>>(qxf, muf, rsf);
    // h2 = relu(bn(qx) @ qW2^T) — K=512 = single panel -> pure sequential fma
    k_gemm_np<true, true><<<dim3(F / 64, BATCH / 64), 256, 0, stream>>>(
        qxf, qW2f, hf, BATCH, F, F, KC, muf, rsf, gamma, beta);
    // fq22 -> qx2
    k_fq22_np<<<BATCH, 256, 0, stream>>>(hf, E3, qxf, dacc + 2);
    // out = qx2 @ W3^T
    k_gemm3<<<BATCH / 4, 256, 0, stream>>>(qxf, W3, out);
    k_findiff<<<1, 64, 0, stream>>>(dacc, out);
}